// Round 6
// baseline (190.256 us; speedup 1.0000x reference)
//
#include <hip/hip_runtime.h>

// B=C=H=W=64, f32.
//   corr[b] = sum_chw map1[b]*map2[b];  corr /= ||corr||;  c = 1-corr;
//   out = map1 + map2 * c[b]
//
// Round 6: discriminate "load starvation" vs "read-path cap".
// Evidence r2-r4: reduce pinned at 2.8 TB/s hot OR cold, and the compiler
// emitted VGPR<=32 every round (refused staging). This round stages via
// __builtin_amdgcn_global_load_lds (VGPR-free, compiler-proof concurrency)
// with hand-counted vmcnt double-buffering. Per-wave LDS slices: each wave
// reads only LDS it wrote -> no barriers in the loop.
//
// Geometry: 1024 blocks (16/batch), 4096 float4 per stream per block.
// Chunk = 256 f4 (4 KB, 16 B/thread). Iteration i consumes k = {2i, 2i+1}
// of both streams = 4 chunks staged into slot set (i&1)*4. 8 iterations.

#define THREADS 256
#define NBATCH 64
#define BPB 16
#define V4B 65536           // float4 per batch per stream
#define V4SEG 4096          // float4 per block per stream

typedef const __attribute__((address_space(1))) void* gptr_t;
typedef __attribute__((address_space(3))) void* lptr_t;

// Stage iteration i's 4 chunks: slots (i&1)*4 + {0:m1 k=2i, 1:m1 k=2i+1,
// 2:m2 k=2i, 3:m2 k=2i+1}. LDS dst is wave-uniform base + lane*16 (HW rule),
// so wave w's instruction covers lds4[slot*256 + w*64 .. +64).
__device__ __forceinline__ void stage(const float4* __restrict__ m1,
                                      const float4* __restrict__ m2,
                                      float4* lds4, int segBase, int i) {
  const int t = threadIdx.x;
  const int w64 = t & ~63;
  const int sb = (i & 1) * 1024;
  const int k0 = 2 * i;
  __builtin_amdgcn_global_load_lds((gptr_t)&m1[segBase + (k0 + 0) * 256 + t],
                                   (lptr_t)&lds4[sb + 0 * 256 + w64], 16, 0, 0);
  __builtin_amdgcn_global_load_lds((gptr_t)&m1[segBase + (k0 + 1) * 256 + t],
                                   (lptr_t)&lds4[sb + 1 * 256 + w64], 16, 0, 0);
  __builtin_amdgcn_global_load_lds((gptr_t)&m2[segBase + (k0 + 0) * 256 + t],
                                   (lptr_t)&lds4[sb + 2 * 256 + w64], 16, 0, 0);
  __builtin_amdgcn_global_load_lds((gptr_t)&m2[segBase + (k0 + 1) * 256 + t],
                                   (lptr_t)&lds4[sb + 3 * 256 + w64], 16, 0, 0);
}

__global__ __launch_bounds__(THREADS, 4) void corr_reduce_kernel(
    const float4* __restrict__ m1, const float4* __restrict__ m2,
    float* __restrict__ partials) {
  __shared__ float4 lds4[2048];        // 32 KB: 8 slots x 256 f4
  __shared__ float wsum[4];
  const int t = threadIdx.x;
  const int b = blockIdx.y;
  const int segBase = b * V4B + blockIdx.x * V4SEG;

  stage(m1, m2, lds4, segBase, 0);
  stage(m1, m2, lds4, segBase, 1);     // 8 wave-ops in flight

  float acc0 = 0.f, acc1 = 0.f, acc2 = 0.f, acc3 = 0.f;
#pragma unroll
  for (int i = 0; i < 8; ++i) {
    // steady state: outstanding = stage(i)[4] + stage(i+1)[4]; wait(4)
    // retires the 4 oldest = stage(i). Last iter: drain.
    if (i < 7) asm volatile("s_waitcnt vmcnt(4)" ::: "memory");
    else       asm volatile("s_waitcnt vmcnt(0)" ::: "memory");
    __builtin_amdgcn_sched_barrier(0);
    const int sb = (i & 1) * 1024;
    const float4 a0 = lds4[sb + t];
    const float4 a1 = lds4[sb + 256 + t];
    const float4 v0 = lds4[sb + 512 + t];
    const float4 v1 = lds4[sb + 768 + t];
    acc0 = fmaf(a0.x, v0.x, acc0); acc1 = fmaf(a0.y, v0.y, acc1);
    acc2 = fmaf(a0.z, v0.z, acc2); acc3 = fmaf(a0.w, v0.w, acc3);
    acc0 = fmaf(a1.x, v1.x, acc0); acc1 = fmaf(a1.y, v1.y, acc1);
    acc2 = fmaf(a1.z, v1.z, acc2); acc3 = fmaf(a1.w, v1.w, acc3);
    if (i < 6) stage(m1, m2, lds4, segBase, i + 2);
  }
  float acc = (acc0 + acc1) + (acc2 + acc3);

#pragma unroll
  for (int off = 32; off > 0; off >>= 1) acc += __shfl_xor(acc, off);
  if ((t & 63) == 0) wsum[t >> 6] = acc;
  __syncthreads();
  if (t == 0)
    partials[b * BPB + blockIdx.x] = (wsum[0] + wsum[1]) + (wsum[2] + wsum[3]);
}

__global__ __launch_bounds__(THREADS, 4) void corr_apply_kernel(
    const float4* __restrict__ m1, const float4* __restrict__ m2,
    const float4* __restrict__ partials4, float4* __restrict__ out) {
  __shared__ float4 lds4[2048];
  const int t = threadIdx.x;
  const int lane = t & 63;
  const int b = blockIdx.y;
  const int segBase = b * V4B + blockIdx.x * V4SEG;

  stage(m1, m2, lds4, segBase, 0);
  stage(m1, m2, lds4, segBase, 1);

  // Barrier-free corr prelude: lane l sums batch l's 16 partial floats
  // (f4 [4l..4l+4)), redundantly per wave. Butterfly -> norm in all lanes.
  float s = 0.f;
#pragma unroll
  for (int j = 0; j < 4; ++j) {
    const float4 p = partials4[4 * lane + j];
    s += (p.x + p.y) + (p.z + p.w);
  }
  float sq = s * s;
#pragma unroll
  for (int off = 32; off > 0; off >>= 1) sq += __shfl_xor(sq, off);
  const float cb = __shfl(s, b);       // corr[b] lives in lane b
  const float c = 1.0f - cb * rsqrtf(sq);

#pragma unroll
  for (int i = 0; i < 8; ++i) {
    // steady: outstanding = stage(i)[4] + stores(i-1)[2] + stage(i+1)[4];
    // newer-than-stage(i) = 6 -> wait(6). Last iter: stage(7) + stores(6)
    // -> wait(2).
    if (i < 7) asm volatile("s_waitcnt vmcnt(6)" ::: "memory");
    else       asm volatile("s_waitcnt vmcnt(2)" ::: "memory");
    __builtin_amdgcn_sched_barrier(0);
    const int sb = (i & 1) * 1024;
    const int k0 = 2 * i;
    const float4 a0 = lds4[sb + t];
    const float4 a1 = lds4[sb + 256 + t];
    const float4 v0 = lds4[sb + 512 + t];
    const float4 v1 = lds4[sb + 768 + t];
    float4 o0, o1;
    o0.x = fmaf(v0.x, c, a0.x); o0.y = fmaf(v0.y, c, a0.y);
    o0.z = fmaf(v0.z, c, a0.z); o0.w = fmaf(v0.w, c, a0.w);
    o1.x = fmaf(v1.x, c, a1.x); o1.y = fmaf(v1.y, c, a1.y);
    o1.z = fmaf(v1.z, c, a1.z); o1.w = fmaf(v1.w, c, a1.w);
    out[segBase + (k0 + 0) * 256 + t] = o0;
    out[segBase + (k0 + 1) * 256 + t] = o1;
    if (i < 6) stage(m1, m2, lds4, segBase, i + 2);
  }
}

extern "C" void kernel_launch(void* const* d_in, const int* in_sizes, int n_in,
                              void* d_out, int out_size, void* d_ws, size_t ws_size,
                              hipStream_t stream) {
  const float4* m1 = (const float4*)d_in[0];
  const float4* m2 = (const float4*)d_in[1];
  float* partials = (float*)d_ws;      // 1024 floats (4 KB) scratch
  float4* out = (float4*)d_out;

  dim3 grid(BPB, NBATCH);
  corr_reduce_kernel<<<grid, THREADS, 0, stream>>>(m1, m2, partials);
  corr_apply_kernel<<<grid, THREADS, 0, stream>>>(m1, m2,
                                                  (const float4*)partials, out);
}

// Round 7
// 189.065 us; speedup vs baseline: 1.0063x; 1.0063x over previous
//
#include <hip/hip_runtime.h>
#include <hip/hip_cooperative_groups.h>

namespace cg = cooperative_groups;

// B=C=H=W=64, f32.
//   corr[b] = sum_chw map1[b]*map2[b];  corr /= ||corr||;  c = 1-corr;
//   out = map1 + map2 * c[b]
//
// Round 7: fused cooperative kernel, de-risked.
// Model (r2-r6): read direction of CU<->L3/HBM caps at ~2.8-3.1 TB/s
// (hot==cold, staging-independent); writes ride the other direction.
// 2-kernel form reads 256 MB -> ~90 us kernel time, at cap. Fusion retains
// m2 on-chip (32 KB LDS + 8 f4/thread regs = full 64 KB m2-block) across a
// grid sync -> 192 MB reads -> ~65 us floor.
// Guard: occupancy query must prove 1024 blocks co-resident; coop failure
// falls back to the proven 2-kernel path in the same call.

#define THREADS 256
#define NBATCH 64
#define BPB 16              // fused/reduce blocks per batch
#define V4B 65536           // float4 per batch per stream
#define V4SEG 4096          // float4 per block per stream (16/thread)
#define K_LDS 8             // m2 float4/thread in LDS (32 KB/block)
#define K_REG 8             // m2 float4/thread in regs
#define ABPB 64             // fallback-apply blocks per batch
#define AV4BLK 1024

__global__ __launch_bounds__(THREADS, 4) void corr_fused_kernel(
    const float4* __restrict__ m1, const float4* __restrict__ m2,
    float* __restrict__ partials, float4* __restrict__ out) {
  __shared__ float4 v_lds[K_LDS * THREADS];   // 32 KB
  __shared__ float wsum[4];

  const int t = threadIdx.x;
  const int b = blockIdx.y;
  const int base = b * V4B + blockIdx.x * V4SEG + t;

  // ---- phase 1: dot partials, retaining all of this block's m2 ----
  float4 vreg[K_REG];
  float acc0 = 0.f, acc1 = 0.f, acc2 = 0.f, acc3 = 0.f;
#pragma unroll
  for (int r = 0; r < 4; ++r) {
    float4 a[4], v[4];
#pragma unroll
    for (int k = 0; k < 4; ++k) a[k] = m1[base + (4 * r + k) * THREADS];
#pragma unroll
    for (int k = 0; k < 4; ++k) v[k] = m2[base + (4 * r + k) * THREADS];
#pragma unroll
    for (int k = 0; k < 4; ++k) {
      const int kk = 4 * r + k;            // compile-time after unroll
      acc0 = fmaf(a[k].x, v[k].x, acc0);
      acc1 = fmaf(a[k].y, v[k].y, acc1);
      acc2 = fmaf(a[k].z, v[k].z, acc2);
      acc3 = fmaf(a[k].w, v[k].w, acc3);
      if (kk < K_LDS) v_lds[kk * THREADS + t] = v[k];
      else            vreg[kk - K_LDS] = v[k];
    }
  }
  float acc = (acc0 + acc1) + (acc2 + acc3);
#pragma unroll
  for (int off = 32; off > 0; off >>= 1) acc += __shfl_xor(acc, off);
  if ((t & 63) == 0) wsum[t >> 6] = acc;
  __syncthreads();
  if (t == 0)
    partials[b * BPB + blockIdx.x] = (wsum[0] + wsum[1]) + (wsum[2] + wsum[3]);
  __threadfence();                         // device-scope release

  cg::this_grid().sync();

  // ---- phase 2: barrier-free per-lane corr; lane l owns batch l ----
  const int lane = t & 63;
  const float4* p4 = (const float4*)partials;
  float s = 0.f;
#pragma unroll
  for (int j = 0; j < 4; ++j) {
    const float4 p = p4[4 * lane + j];     // floats [16l,16l+16) = batch l
    s += (p.x + p.y) + (p.z + p.w);
  }
  float sq = s * s;
#pragma unroll
  for (int off = 32; off > 0; off >>= 1) sq += __shfl_xor(sq, off);
  const float cb = __shfl(s, b);           // corr[b] lives in lane b
  const float c = 1.0f - cb * rsqrtf(sq);

  // ---- phase 3: out = fma(m2_retained, c, m1_reread) ----
#pragma unroll
  for (int r = 0; r < 4; ++r) {
    float4 a[4];
#pragma unroll
    for (int k = 0; k < 4; ++k) a[k] = m1[base + (4 * r + k) * THREADS];
#pragma unroll
    for (int k = 0; k < 4; ++k) {
      const int kk = 4 * r + k;
      const float4 v = (kk < K_LDS) ? v_lds[kk * THREADS + t]
                                    : vreg[kk - K_LDS];
      float4 o;
      o.x = fmaf(v.x, c, a[k].x);
      o.y = fmaf(v.y, c, a[k].y);
      o.z = fmaf(v.z, c, a[k].z);
      o.w = fmaf(v.w, c, a[k].w);
      out[base + (4 * r + k) * THREADS] = o;
    }
  }
}

// ---------------- fallback path (r3/r4-proven) ----------------

__global__ __launch_bounds__(THREADS, 4) void corr_reduce_kernel(
    const float4* __restrict__ m1, const float4* __restrict__ m2,
    float* __restrict__ partials) {
  const int b = blockIdx.y;
  const int base = b * V4B + blockIdx.x * V4SEG + threadIdx.x;

  float acc0 = 0.f, acc1 = 0.f, acc2 = 0.f, acc3 = 0.f;
#pragma unroll
  for (int r = 0; r < 4; ++r) {
    float4 a[4], v[4];
#pragma unroll
    for (int k = 0; k < 4; ++k) a[k] = m1[base + (4 * r + k) * THREADS];
#pragma unroll
    for (int k = 0; k < 4; ++k) v[k] = m2[base + (4 * r + k) * THREADS];
#pragma unroll
    for (int k = 0; k < 4; ++k) {
      acc0 = fmaf(a[k].x, v[k].x, acc0);
      acc1 = fmaf(a[k].y, v[k].y, acc1);
      acc2 = fmaf(a[k].z, v[k].z, acc2);
      acc3 = fmaf(a[k].w, v[k].w, acc3);
    }
  }
  float acc = (acc0 + acc1) + (acc2 + acc3);
#pragma unroll
  for (int off = 32; off > 0; off >>= 1) acc += __shfl_xor(acc, off);
  __shared__ float wsum[4];
  if ((threadIdx.x & 63) == 0) wsum[threadIdx.x >> 6] = acc;
  __syncthreads();
  if (threadIdx.x == 0)
    partials[b * BPB + blockIdx.x] = (wsum[0] + wsum[1]) + (wsum[2] + wsum[3]);
}

__global__ __launch_bounds__(THREADS, 4) void corr_apply_kernel(
    const float4* __restrict__ m1, const float4* __restrict__ m2,
    const float4* __restrict__ partials4, float4* __restrict__ out) {
  const int b = blockIdx.y;
  const int base = b * V4B + blockIdx.x * AV4BLK + threadIdx.x;

  float4 a[4], v[4];
#pragma unroll
  for (int k = 0; k < 4; ++k) a[k] = m1[base + k * THREADS];
#pragma unroll
  for (int k = 0; k < 4; ++k) v[k] = m2[base + k * THREADS];

  const float4 p = partials4[threadIdx.x];   // f4 t = batch t/4
  __builtin_amdgcn_sched_barrier(0);

  float s = (p.x + p.y) + (p.z + p.w);
  s += __shfl_xor(s, 1);
  s += __shfl_xor(s, 2);

  __shared__ float csh[NBATCH];
  __shared__ float c_sh;
  if ((threadIdx.x & 3) == 0) csh[threadIdx.x >> 2] = s;
  __syncthreads();
  if (threadIdx.x < 64) {
    float cv = csh[threadIdx.x];
    float sq = cv * cv;
#pragma unroll
    for (int off = 32; off > 0; off >>= 1) sq += __shfl_xor(sq, off);
    if (threadIdx.x == 0) c_sh = 1.0f - csh[b] * rsqrtf(sq);
  }
  __syncthreads();
  const float c = c_sh;

#pragma unroll
  for (int k = 0; k < 4; ++k) {
    float4 o;
    o.x = fmaf(v[k].x, c, a[k].x);
    o.y = fmaf(v[k].y, c, a[k].y);
    o.z = fmaf(v[k].z, c, a[k].z);
    o.w = fmaf(v[k].w, c, a[k].w);
    out[base + k * THREADS] = o;
  }
}

extern "C" void kernel_launch(void* const* d_in, const int* in_sizes, int n_in,
                              void* d_out, int out_size, void* d_ws, size_t ws_size,
                              hipStream_t stream) {
  const float4* m1 = (const float4*)d_in[0];
  const float4* m2 = (const float4*)d_in[1];
  float* partials = (float*)d_ws;          // 1024 floats (4 KB) scratch
  float4* out = (float4*)d_out;

  dim3 grid(BPB, NBATCH);                  // 1024 blocks

  // Guard: only attempt cooperative if 1024 blocks provably co-resident.
  hipError_t err = hipErrorUnknown;
  int occ = 0, ncu = 0, dev = 0;
  if (hipGetDevice(&dev) == hipSuccess &&
      hipDeviceGetAttribute(&ncu, hipDeviceAttributeMultiprocessorCount,
                            dev) == hipSuccess &&
      hipOccupancyMaxActiveBlocksPerMultiprocessor(
          &occ, corr_fused_kernel, THREADS, 0) == hipSuccess &&
      occ * ncu >= BPB * NBATCH) {
    void* args[] = {(void*)&m1, (void*)&m2, (void*)&partials, (void*)&out};
    err = hipLaunchCooperativeKernel(corr_fused_kernel, grid, dim3(THREADS),
                                     args, 0, stream);
  }

  if (err != hipSuccess) {
    (void)hipGetLastError();               // clear sticky error, keep stream clean
    dim3 agrid(ABPB, NBATCH);
    corr_reduce_kernel<<<grid, THREADS, 0, stream>>>(m1, m2, partials);
    corr_apply_kernel<<<agrid, THREADS, 0, stream>>>(
        m1, m2, (const float4*)partials, out);
  }
}